// Round 4
// baseline (261.846 us; speedup 1.0000x reference)
//
#include <hip/hip_runtime.h>

#define NN 20000
#define NE 320000
#define NG 256
#define CAPD 48           // dst-side bucket capacity (yq rows); P(deg>48) ~ 1e-12
#define ZS 148            // Ztab row stride (147 used)
#define YQS 32            // yq row stride in floats = 128 B = exactly one cache line
#define PROWS 32          // partial spread rows
#define BINS 10           // src-range bins (bin = s >> 11); Ztab slice 1.2 MB < 4 MB L2/XCD
#define BINSH 11
#define NBLK 1250         // binsort blocks (256 edges each)
#define BINW 64           // slots per (block,bin); Binom(256,0.102) mean 26.2 sd 4.9 -> safe
#define RECF 12           // record floats: [ea(7) | pk(int: p | bg<<21) | s(int) | px py pz]

// binbuf layout: [bin][block][BINW] records -> bin-major keeps consumer L2-local.
// cnt[bin*NBLK + block] = stored records in that run (written unconditionally every pass).
// yq row (32 floats): [y(21) | sh(8) | 0,0,0]  -- one aligned 128 B line per edge.
// y col = g*7+v; scale factors folded into WV.

// ---------------- K0: WV[u][147] = folded W*V weights (tiny) ----------------

__global__ __launch_bounds__(256) void k_wv(
    const float* __restrict__ W1, const float* __restrict__ W2,
    const float* __restrict__ W3, const float* __restrict__ V1,
    const float* __restrict__ V2, const float* __restrict__ V3,
    float* __restrict__ WV)
{
    const int idx = blockIdx.x * 256 + threadIdx.x;   // 23*147 = 3381
    if (idx < 23 * 147) {
        const int u = idx / 147, c = idx - u * 147;
        const int vp = c / 21, col = c - vp * 21;
        const int g = col / 7, v = col - g * 7;
        float sum = 0.f;
        if (g == 0) {
            for (int w = 0; w < 64; ++w)
                sum += W1[(u*7 + vp)*64 + w] * V1[w*7 + v];
            sum *= 0.07881104f * 0.04724556f;   // a1 * 1/sqrt(64*7)
        } else if (g == 1) {
            for (int w = 0; w < 24; ++w)
                sum += W2[(u*7 + vp)*24 + w] * V2[w*7 + v];
            sum *= 0.07881104f * 0.04454354f;   // a1 * 1/sqrt(24*7*3)
        } else {
            for (int w = 0; w < 16; ++w)
                sum += W3[(u*7 + vp)*16 + w] * V3[w*7 + v];
            sum *= 0.07881104f * 0.04225771f;   // a1 * 1/sqrt(16*7*5)
        }
        WV[idx] = sum;                           // [u][147], c = v'*21 + col
    }
}

// ---------------- K1: slotted bin scatter -- no barriers around global atomics ----------------

__global__ __launch_bounds__(256) void k_binsort(
    const float* __restrict__ pos,
    const float* __restrict__ eag,
    const int* __restrict__ esrc,
    const int* __restrict__ edst,
    const int* __restrict__ batch,
    int* __restrict__ deg_d,
    int* __restrict__ cnt,
    float* __restrict__ binbuf)
{
    __shared__ int off[BINS];
    const int t = threadIdx.x, bb = blockIdx.x;
    const int e = bb * 256 + t;               // NBLK*256 == NE
    if (t < BINS) off[t] = 0;

    const int s = esrc[e], d = edst[e];
    const int bin = s >> BINSH;
    const int sd = atomicAdd(&deg_d[d], 1);   // fired early, used only at the store
    const int bg = batch[d];
    float ea[7];
#pragma unroll
    for (int v = 0; v < 7; ++v) ea[v] = eag[(size_t)e * 7 + v];
    const float px = pos[3*s+0] - pos[3*d+0];
    const float py = pos[3*s+1] - pos[3*d+1];
    const float pz = pos[3*s+2] - pos[3*d+2];

    __syncthreads();                          // off init visible (LDS only)
    const bool ok = (sd < CAPD);              // overflow edge dropped (P ~ 0)
    int slot = BINW;
    if (ok) slot = atomicAdd(&off[bin], 1);   // LDS atomic, no global sequencing
    if (ok && slot < BINW) {
        const int pk = (d * CAPD + sd) | (bg << 21);   // p < 960000 < 2^20
        float4* r = (float4*)(binbuf + (((size_t)bin * NBLK + bb) * BINW + slot) * RECF);
        r[0] = make_float4(ea[0], ea[1], ea[2], ea[3]);
        r[1] = make_float4(ea[4], ea[5], ea[6], __int_as_float(pk));
        r[2] = make_float4(__int_as_float(s), px, py, pz);
    }
    __syncthreads();
    if (t < BINS) cnt[t * NBLK + bb] = min(off[t], BINW);
}

// ---------------- K2: Ztab[n][c] = sum_u x[n][u] * WV[u][c]  (8 nodes/block) ----------------

__global__ __launch_bounds__(256) void k_ztab(const float* __restrict__ x,
                                              const float* __restrict__ WV,
                                              float* __restrict__ Ztab)
{
    __shared__ float xa[8][23];
    const int b = blockIdx.x, t = threadIdx.x;   // grid 2500 exact
    const int base = b * 8;
    if (t < 184) {
        const int nl = t / 23, u = t - nl * 23;
        xa[nl][u] = x[(size_t)(base + nl) * 23 + u];
    }
    __syncthreads();
    if (t < 147) {
        float acc[8];
#pragma unroll
        for (int n = 0; n < 8; ++n) acc[n] = 0.f;
        for (int u = 0; u < 23; ++u) {
            const float wv = WV[u * 147 + t];     // coalesced
#pragma unroll
            for (int n = 0; n < 8; ++n) acc[n] += xa[n][u] * wv;
        }
#pragma unroll
        for (int n = 0; n < 8; ++n)
            Ztab[(size_t)(base + n) * ZS + t] = acc[n];
    }
}

// ---------------- K3: slot-parallel; 32 lanes/record -> one 128 B yq line ----------
// Slots walked bin-by-bin => Ztab slice (1.2 MB) stays L2-resident.

__global__ __launch_bounds__(256) void k_yedge(const float* __restrict__ Ztab,
                                               const float* __restrict__ binbuf,
                                               const int* __restrict__ cnt,
                                               float* __restrict__ yq)
{
    const int t = threadIdx.x;
    const int bid = blockIdx.x;                 // grid = BINS * (NBLK*BINW/8)
    const int bin = bid / (NBLK * BINW / 8);
    const int sp  = (bid % (NBLK * BINW / 8)) * 8 + (t >> 5);
    const int bb  = sp >> 6, idx = sp & (BINW - 1);
    if (idx >= cnt[bin * NBLK + bb]) return;    // per-group exec mask

    const float* rec = binbuf + (((size_t)bin * NBLK + bb) * BINW + idx) * RECF;
    const int col = t & 31;
    const int p = ((const int*)rec)[7] & 0x1FFFFF;

    float val;
    if (col < 21) {
        const int s = ((const int*)rec)[8];
        const float* z = Ztab + (size_t)s * ZS;
        float y = 0.f;
#pragma unroll
        for (int v = 0; v < 7; ++v)
            y += rec[v] * z[21 * v + col];
        val = y;
    } else if (col < 29) {
        const float px = rec[9], py = rec[10], pz = rec[11];
        const float r2 = px*px + py*py + pz*pz;
        const float h0 = 1.7320508f*px, h1 = 1.7320508f*py, h2 = 1.7320508f*pz;
        const float h3 = 3.8729833f*px*py, h4 = 3.8729833f*py*pz;
        const float h5 = 1.1180340f*(3.f*pz*pz - r2);
        const float h6 = 3.8729833f*px*pz;
        const float h7 = 1.9364917f*(px*px - py*py);
        const int c = col - 21;
        val = (c == 0) ? h0 : (c == 1) ? h1 : (c == 2) ? h2 : (c == 3) ? h3
            : (c == 4) ? h4 : (c == 5) ? h5 : (c == 6) ? h6 : h7;
    } else {
        val = 0.f;
    }
    yq[(size_t)p * YQS + col] = val;            // one aligned 128 B line per record
}

// ---------------- K4: wave per dst node; single-stream reduction of its bucket ----------------
// rtab row (64 fp32): [r0[v](7) | r1[m,v] m-major (21) | r2[m,v] m-major (35) | pad]

__global__ __launch_bounds__(256) void k_racc(const float* __restrict__ yq,
                                              const int* __restrict__ deg_d,
                                              float* __restrict__ rtab)
{
    const int t = threadIdx.x, lane = t & 63;
    const int node = __builtin_amdgcn_readfirstlane(blockIdx.x * 4 + (t >> 6));
    const int dg = min(deg_d[node], CAPD);

    int col, sidx; bool unit;
    if (lane < 7)       { col = lane;              sidx = 0;          unit = true;  }
    else if (lane < 28) { const int i = lane - 7;  col = 7  + i % 7;  sidx = i / 7;     unit = false; }
    else if (lane < 63) { const int i = lane - 28; col = 14 + i % 7;  sidx = 3 + i / 7; unit = false; }
    else                { col = 0;                 sidx = 0;          unit = true;  }

    const float* yb = yq + (size_t)node * (CAPD * YQS);

    float acc = 0.f;
    int r = 0;
    for (; r + 4 <= dg; r += 4) {
        float yv[4], sv[4];
#pragma unroll
        for (int k = 0; k < 4; ++k) yv[k] = yb[(r + k) * YQS + col];
#pragma unroll
        for (int k = 0; k < 4; ++k) sv[k] = yb[(r + k) * YQS + 21 + sidx];
#pragma unroll
        for (int k = 0; k < 4; ++k) acc += (unit ? 1.f : sv[k]) * yv[k];
    }
    for (; r < dg; ++r) {
        const float yv = yb[r * YQS + col];
        const float sv = yb[r * YQS + 21 + sidx];
        acc += (unit ? 1.f : sv) * yv;
    }

    rtab[(size_t)node * 64 + lane] = (lane < 63) ? acc : 0.f;
}

// ---------------- K5: slot-parallel; 8 lanes/record; rtab slice L2-resident ----

__global__ __launch_bounds__(256) void k_gfinal(const float* __restrict__ rtab,
                                                const float* __restrict__ binbuf,
                                                const int* __restrict__ cnt,
                                                float* __restrict__ partial)
{
    __shared__ float bins_s[NG];
    const int t = threadIdx.x;
    const int bid = blockIdx.x;                 // grid = BINS * (NBLK*BINW/32)
    const int bin = bid / (NBLK * BINW / 32);
    const int sp  = (bid % (NBLK * BINW / 32)) * 32 + (t >> 3);
    const int bb  = sp >> 6, idx = sp & (BINW - 1);
    const int v = t & 7;                        // v = 0..6 active, lane 7 dummy

    bins_s[t] = 0.f;
    __syncthreads();

    if (idx < cnt[bin * NBLK + bb]) {
        const float* rec = binbuf + (((size_t)bin * NBLK + bb) * BINW + idx) * RECF;
        const int pk = ((const int*)rec)[7];
        const int bg = ((unsigned)pk) >> 21;
        const int s  = ((const int*)rec)[8];
        const float px = rec[9], py = rec[10], pz = rec[11];
        const float r2 = px*px + py*py + pz*pz;
        const float h0 = 1.7320508f*px, h1 = 1.7320508f*py, h2 = 1.7320508f*pz;
        const float h3 = 3.8729833f*px*py, h4 = 3.8729833f*py*pz;
        const float h5 = 1.1180340f*(3.f*pz*pz - r2);
        const float h6 = 3.8729833f*px*pz;
        const float h7 = 1.9364917f*(px*px - py*py);

        const float* r = rtab + (size_t)s * 64;
        const float eav = (v < 7) ? rec[v] : 0.f;

        float tsum = r[v];                      // shfac[0] = 1
        tsum += h0 * r[ 7 + v];
        tsum += h1 * r[14 + v];
        tsum += h2 * r[21 + v];
        tsum += h3 * r[28 + v];
        tsum += h4 * r[35 + v];
        tsum += h5 * r[42 + v];
        tsum += h6 * r[49 + v];
        tsum += h7 * r[56 + v];

        float g = eav * tsum;
        g += __shfl_xor(g, 1);                  // reduce 8-lane group
        g += __shfl_xor(g, 2);
        g += __shfl_xor(g, 4);
        if (v == 0) atomicAdd(&bins_s[bg], g);  // LDS atomic, 1 per record
    }

    __syncthreads();
    unsafeAtomicAdd(&partial[(bid & (PROWS - 1)) * NG + t], bins_s[t]);
}

// ---------------- K6: reduce PROWS partial rows -> out ----------------

__global__ __launch_bounds__(256) void k_reduce(const float* __restrict__ partial,
                                                float* __restrict__ out)
{
    const int t = threadIdx.x;
    float s = 0.f;
#pragma unroll
    for (int i = 0; i < PROWS; ++i) s += partial[i * NG + t];
    out[t] = s;
}

extern "C" void kernel_launch(void* const* d_in, const int* in_sizes, int n_in,
                              void* d_out, int out_size, void* d_ws, size_t ws_size,
                              hipStream_t stream)
{
    const float* pos  = (const float*)d_in[0];
    const float* x    = (const float*)d_in[1];
    const float* eag  = (const float*)d_in[2];
    const int*   eidx = (const int*)d_in[3];
    const int*   batch= (const int*)d_in[4];
    const float* W1   = (const float*)d_in[5];
    const float* W2   = (const float*)d_in[6];
    const float* W3   = (const float*)d_in[7];
    const float* V1   = (const float*)d_in[8];
    const float* V2   = (const float*)d_in[9];
    const float* V3   = (const float*)d_in[10];
    const int* esrc = eidx;
    const int* edst = eidx + NE;

    char* ws = (char*)d_ws;
    size_t off = 0;
    auto alloc = [&](size_t bytes) -> void* {
        void* p = ws + off;
        off = (off + bytes + 255) & ~(size_t)255;
        return p;
    };
    float* yq     = (float*)alloc((size_t)NN * CAPD * YQS * sizeof(float)); // 122.9 MB
    float* binbuf = (float*)alloc((size_t)BINS * NBLK * BINW * RECF * sizeof(float)); // 38.4 MB
    float* Ztab   = (float*)alloc((size_t)NN * ZS * sizeof(float));         // 11.8 MB
    float* rtab   = (float*)alloc((size_t)NN * 64 * sizeof(float));         // 5.1 MB
    float* WV     = (float*)alloc((size_t)23 * 147 * sizeof(float));        // 13.5 KB
    int*   cnt    = (int*)alloc((size_t)BINS * NBLK * sizeof(int));         // 50 KB (rewritten)
    int*   deg_d  = (int*)alloc((size_t)NN * sizeof(int));     // ---- zeroed region
    float* partial= (float*)alloc((size_t)PROWS * NG * sizeof(float));
    char*  zend   = (char*)ws + off;

    hipMemsetAsync(deg_d, 0, (size_t)(zend - (char*)deg_d), stream);

    k_wv<<<14, 256, 0, stream>>>(W1, W2, W3, V1, V2, V3, WV);
    k_binsort<<<NBLK, 256, 0, stream>>>(pos, eag, esrc, edst, batch,
                                        deg_d, cnt, binbuf);
    k_ztab<<<NN/8, 256, 0, stream>>>(x, WV, Ztab);
    k_yedge<<<BINS * (NBLK * BINW / 8), 256, 0, stream>>>(Ztab, binbuf, cnt, yq);
    k_racc<<<NN/4, 256, 0, stream>>>(yq, deg_d, rtab);
    k_gfinal<<<BINS * (NBLK * BINW / 32), 256, 0, stream>>>(rtab, binbuf, cnt, partial);
    k_reduce<<<1, 256, 0, stream>>>(partial, (float*)d_out);
}

// Round 5
// 191.875 us; speedup vs baseline: 1.3647x; 1.3647x over previous
//
#include <hip/hip_runtime.h>

#define NN 20000
#define NE 320000
#define NG 256
#define CAPD 48           // dst-side bucket capacity (yq rows); P(deg>48) ~ 1e-12
#define ZS 148            // Ztab row stride (147 used)
#define YQS 32            // yq row stride in floats = 128 B = exactly one cache line
#define PROWS 32          // partial spread rows
#define BINS 10           // src-range bins (bin = s >> 11); Ztab slice 1.2 MB < 4 MB L2/XCD
#define BINSH 11
#define NBLK 1250         // binsort blocks (256 edges each)
#define BINW 64           // slots per (block,bin); Binom(256,0.102) mean 26.2 sd 4.9 -> safe
#define RECF 12           // record floats: [ea(7) | pk(int: p | bg<<21) | s(int) | px py pz]
#define BPB_Y 250         // yedge blocks per bin  -> 5 runs/block, grid 2500
#define BPB_G 125         // gfinal blocks per bin -> 10 runs/block, grid 1250

// binbuf layout: [bin][block][BINW] records -> bin-major keeps consumer L2-local.
// cnt[bin*NBLK + block] = records in that run (dense from slot 0).
// Consumers are persistent loop-strided blocks: few blocks, many records each,
// so the rec->Ztab dependent chain pipelines across loop iterations (round-4 fix).
// yq row (32 floats): [y(21) | sh(8) | 0,0,0]  -- one aligned 128 B line per edge.
// y col = g*7+v; scale factors folded into WV.

// ---------------- K0: WV[u][147] = folded W*V weights (tiny) ----------------

__global__ __launch_bounds__(256) void k_wv(
    const float* __restrict__ W1, const float* __restrict__ W2,
    const float* __restrict__ W3, const float* __restrict__ V1,
    const float* __restrict__ V2, const float* __restrict__ V3,
    float* __restrict__ WV)
{
    const int idx = blockIdx.x * 256 + threadIdx.x;   // 23*147 = 3381
    if (idx < 23 * 147) {
        const int u = idx / 147, c = idx - u * 147;
        const int vp = c / 21, col = c - vp * 21;
        const int g = col / 7, v = col - g * 7;
        float sum = 0.f;
        if (g == 0) {
            for (int w = 0; w < 64; ++w)
                sum += W1[(u*7 + vp)*64 + w] * V1[w*7 + v];
            sum *= 0.07881104f * 0.04724556f;   // a1 * 1/sqrt(64*7)
        } else if (g == 1) {
            for (int w = 0; w < 24; ++w)
                sum += W2[(u*7 + vp)*24 + w] * V2[w*7 + v];
            sum *= 0.07881104f * 0.04454354f;   // a1 * 1/sqrt(24*7*3)
        } else {
            for (int w = 0; w < 16; ++w)
                sum += W3[(u*7 + vp)*16 + w] * V3[w*7 + v];
            sum *= 0.07881104f * 0.04225771f;   // a1 * 1/sqrt(16*7*5)
        }
        WV[idx] = sum;                           // [u][147], c = v'*21 + col
    }
}

// ---------------- K1: slotted bin scatter -- no barriers around global atomics ----------------

__global__ __launch_bounds__(256) void k_binsort(
    const float* __restrict__ pos,
    const float* __restrict__ eag,
    const int* __restrict__ esrc,
    const int* __restrict__ edst,
    const int* __restrict__ batch,
    int* __restrict__ deg_d,
    int* __restrict__ cnt,
    float* __restrict__ binbuf)
{
    __shared__ int off[BINS];
    const int t = threadIdx.x, bb = blockIdx.x;
    const int e = bb * 256 + t;               // NBLK*256 == NE
    if (t < BINS) off[t] = 0;

    const int s = esrc[e], d = edst[e];
    const int bin = s >> BINSH;
    const int sd = atomicAdd(&deg_d[d], 1);   // fired early, used only at the store
    const int bg = batch[d];
    float ea[7];
#pragma unroll
    for (int v = 0; v < 7; ++v) ea[v] = eag[(size_t)e * 7 + v];
    const float px = pos[3*s+0] - pos[3*d+0];
    const float py = pos[3*s+1] - pos[3*d+1];
    const float pz = pos[3*s+2] - pos[3*d+2];

    __syncthreads();                          // off init visible (LDS only)
    const bool ok = (sd < CAPD);              // overflow edge dropped (P ~ 0)
    int slot = BINW;
    if (ok) slot = atomicAdd(&off[bin], 1);   // LDS atomic, no global sequencing
    if (ok && slot < BINW) {
        const int pk = (d * CAPD + sd) | (bg << 21);   // p < 960000 < 2^20
        float4* r = (float4*)(binbuf + (((size_t)bin * NBLK + bb) * BINW + slot) * RECF);
        r[0] = make_float4(ea[0], ea[1], ea[2], ea[3]);
        r[1] = make_float4(ea[4], ea[5], ea[6], __int_as_float(pk));
        r[2] = make_float4(__int_as_float(s), px, py, pz);
    }
    __syncthreads();
    if (t < BINS) cnt[t * NBLK + bb] = min(off[t], BINW);
}

// ---------------- K2: Ztab[n][c] = sum_u x[n][u] * WV[u][c]  (8 nodes/block) ----------------

__global__ __launch_bounds__(256) void k_ztab(const float* __restrict__ x,
                                              const float* __restrict__ WV,
                                              float* __restrict__ Ztab)
{
    __shared__ float xa[8][23];
    const int b = blockIdx.x, t = threadIdx.x;   // grid 2500 exact
    const int base = b * 8;
    if (t < 184) {
        const int nl = t / 23, u = t - nl * 23;
        xa[nl][u] = x[(size_t)(base + nl) * 23 + u];
    }
    __syncthreads();
    if (t < 147) {
        float acc[8];
#pragma unroll
        for (int n = 0; n < 8; ++n) acc[n] = 0.f;
        for (int u = 0; u < 23; ++u) {
            const float wv = WV[u * 147 + t];     // coalesced
#pragma unroll
            for (int n = 0; n < 8; ++n) acc[n] += xa[n][u] * wv;
        }
#pragma unroll
        for (int n = 0; n < 8; ++n)
            Ztab[(size_t)(base + n) * ZS + t] = acc[n];
    }
}

// ---------------- K3: persistent blocks; 32 lanes/record; loop over runs+slots ----------
// Walk order bin-major => Ztab slice (1.2 MB) stays L2-resident.

__global__ __launch_bounds__(256) void k_yedge(const float* __restrict__ Ztab,
                                               const float* __restrict__ binbuf,
                                               const int* __restrict__ cnt,
                                               float* __restrict__ yq)
{
    const int t = threadIdx.x;
    const int bin = blockIdx.x / BPB_Y;         // grid = BINS * BPB_Y = 2500
    const int bb0 = blockIdx.x % BPB_Y;
    const int grp = t >> 5, col = t & 31;       // 8 groups of 32 lanes

    for (int bb = bb0; bb < NBLK; bb += BPB_Y) {
        const int cn = cnt[bin * NBLK + bb];    // uniform per block -> scalar load
        const float* run = binbuf + ((size_t)(bin * NBLK + bb) * BINW) * RECF;
        for (int idx = grp; idx < cn; idx += 8) {
            const float* rec = run + (size_t)idx * RECF;
            const int p = ((const int*)rec)[7] & 0x1FFFFF;
            float val;
            if (col < 21) {
                const int s = ((const int*)rec)[8];
                const float* z = Ztab + (size_t)s * ZS;
                float y = 0.f;
#pragma unroll
                for (int v = 0; v < 7; ++v)
                    y += rec[v] * z[21 * v + col];
                val = y;
            } else if (col < 29) {
                const float px = rec[9], py = rec[10], pz = rec[11];
                const float r2 = px*px + py*py + pz*pz;
                const float h0 = 1.7320508f*px, h1 = 1.7320508f*py, h2 = 1.7320508f*pz;
                const float h3 = 3.8729833f*px*py, h4 = 3.8729833f*py*pz;
                const float h5 = 1.1180340f*(3.f*pz*pz - r2);
                const float h6 = 3.8729833f*px*pz;
                const float h7 = 1.9364917f*(px*px - py*py);
                const int c = col - 21;
                val = (c == 0) ? h0 : (c == 1) ? h1 : (c == 2) ? h2 : (c == 3) ? h3
                    : (c == 4) ? h4 : (c == 5) ? h5 : (c == 6) ? h6 : h7;
            } else {
                val = 0.f;
            }
            yq[(size_t)p * YQS + col] = val;    // one aligned 128 B line per record
        }
    }
}

// ---------------- K4: wave per dst node; single-stream reduction of its bucket ----------------
// rtab row (64 fp32): [r0[v](7) | r1[m,v] m-major (21) | r2[m,v] m-major (35) | pad]

__global__ __launch_bounds__(256) void k_racc(const float* __restrict__ yq,
                                              const int* __restrict__ deg_d,
                                              float* __restrict__ rtab)
{
    const int t = threadIdx.x, lane = t & 63;
    const int node = __builtin_amdgcn_readfirstlane(blockIdx.x * 4 + (t >> 6));
    const int dg = min(deg_d[node], CAPD);

    int col, sidx; bool unit;
    if (lane < 7)       { col = lane;              sidx = 0;          unit = true;  }
    else if (lane < 28) { const int i = lane - 7;  col = 7  + i % 7;  sidx = i / 7;     unit = false; }
    else if (lane < 63) { const int i = lane - 28; col = 14 + i % 7;  sidx = 3 + i / 7; unit = false; }
    else                { col = 0;                 sidx = 0;          unit = true;  }

    const float* yb = yq + (size_t)node * (CAPD * YQS);

    float acc = 0.f;
    int r = 0;
    for (; r + 4 <= dg; r += 4) {
        float yv[4], sv[4];
#pragma unroll
        for (int k = 0; k < 4; ++k) yv[k] = yb[(r + k) * YQS + col];
#pragma unroll
        for (int k = 0; k < 4; ++k) sv[k] = yb[(r + k) * YQS + 21 + sidx];
#pragma unroll
        for (int k = 0; k < 4; ++k) acc += (unit ? 1.f : sv[k]) * yv[k];
    }
    for (; r < dg; ++r) {
        const float yv = yb[r * YQS + col];
        const float sv = yb[r * YQS + 21 + sidx];
        acc += (unit ? 1.f : sv) * yv;
    }

    rtab[(size_t)node * 64 + lane] = (lane < 63) ? acc : 0.f;
}

// ---------------- K5: persistent blocks; 8 lanes/record; rtab slice L2-resident ----

__global__ __launch_bounds__(256) void k_gfinal(const float* __restrict__ rtab,
                                                const float* __restrict__ binbuf,
                                                const int* __restrict__ cnt,
                                                float* __restrict__ partial)
{
    __shared__ float bins_s[NG];
    const int t = threadIdx.x;
    const int bin = blockIdx.x / BPB_G;         // grid = BINS * BPB_G = 1250
    const int bb0 = blockIdx.x % BPB_G;
    const int grp = t >> 3, v = t & 7;          // 32 groups; v = 0..6 active

    bins_s[t] = 0.f;
    __syncthreads();

    for (int bb = bb0; bb < NBLK; bb += BPB_G) {
        const int cn = cnt[bin * NBLK + bb];    // uniform per block -> scalar load
        const float* run = binbuf + ((size_t)(bin * NBLK + bb) * BINW) * RECF;
        for (int idx = grp; idx < cn; idx += 32) {
            const float* rec = run + (size_t)idx * RECF;
            const int pk = ((const int*)rec)[7];
            const int bg = ((unsigned)pk) >> 21;
            const int s  = ((const int*)rec)[8];
            const float px = rec[9], py = rec[10], pz = rec[11];
            const float r2 = px*px + py*py + pz*pz;
            const float h0 = 1.7320508f*px, h1 = 1.7320508f*py, h2 = 1.7320508f*pz;
            const float h3 = 3.8729833f*px*py, h4 = 3.8729833f*py*pz;
            const float h5 = 1.1180340f*(3.f*pz*pz - r2);
            const float h6 = 3.8729833f*px*pz;
            const float h7 = 1.9364917f*(px*px - py*py);

            const float* r = rtab + (size_t)s * 64;
            const float eav = (v < 7) ? rec[v] : 0.f;

            float tsum = r[v];                  // shfac[0] = 1
            tsum += h0 * r[ 7 + v];
            tsum += h1 * r[14 + v];
            tsum += h2 * r[21 + v];
            tsum += h3 * r[28 + v];
            tsum += h4 * r[35 + v];
            tsum += h5 * r[42 + v];
            tsum += h6 * r[49 + v];
            tsum += h7 * r[56 + v];

            float g = eav * tsum;
            g += __shfl_xor(g, 1);              // reduce 8-lane group
            g += __shfl_xor(g, 2);
            g += __shfl_xor(g, 4);
            if (v == 0) atomicAdd(&bins_s[bg], g);  // LDS atomic, 1 per record
        }
    }

    __syncthreads();
    unsafeAtomicAdd(&partial[(blockIdx.x & (PROWS - 1)) * NG + t], bins_s[t]);
}

// ---------------- K6: reduce PROWS partial rows -> out ----------------

__global__ __launch_bounds__(256) void k_reduce(const float* __restrict__ partial,
                                                float* __restrict__ out)
{
    const int t = threadIdx.x;
    float s = 0.f;
#pragma unroll
    for (int i = 0; i < PROWS; ++i) s += partial[i * NG + t];
    out[t] = s;
}

extern "C" void kernel_launch(void* const* d_in, const int* in_sizes, int n_in,
                              void* d_out, int out_size, void* d_ws, size_t ws_size,
                              hipStream_t stream)
{
    const float* pos  = (const float*)d_in[0];
    const float* x    = (const float*)d_in[1];
    const float* eag  = (const float*)d_in[2];
    const int*   eidx = (const int*)d_in[3];
    const int*   batch= (const int*)d_in[4];
    const float* W1   = (const float*)d_in[5];
    const float* W2   = (const float*)d_in[6];
    const float* W3   = (const float*)d_in[7];
    const float* V1   = (const float*)d_in[8];
    const float* V2   = (const float*)d_in[9];
    const float* V3   = (const float*)d_in[10];
    const int* esrc = eidx;
    const int* edst = eidx + NE;

    char* ws = (char*)d_ws;
    size_t off = 0;
    auto alloc = [&](size_t bytes) -> void* {
        void* p = ws + off;
        off = (off + bytes + 255) & ~(size_t)255;
        return p;
    };
    float* yq     = (float*)alloc((size_t)NN * CAPD * YQS * sizeof(float)); // 122.9 MB
    float* binbuf = (float*)alloc((size_t)BINS * NBLK * BINW * RECF * sizeof(float)); // 38.4 MB
    float* Ztab   = (float*)alloc((size_t)NN * ZS * sizeof(float));         // 11.8 MB
    float* rtab   = (float*)alloc((size_t)NN * 64 * sizeof(float));         // 5.1 MB
    float* WV     = (float*)alloc((size_t)23 * 147 * sizeof(float));        // 13.5 KB
    int*   cnt    = (int*)alloc((size_t)BINS * NBLK * sizeof(int));         // 50 KB (rewritten)
    int*   deg_d  = (int*)alloc((size_t)NN * sizeof(int));     // ---- zeroed region
    float* partial= (float*)alloc((size_t)PROWS * NG * sizeof(float));
    char*  zend   = (char*)ws + off;

    hipMemsetAsync(deg_d, 0, (size_t)(zend - (char*)deg_d), stream);

    k_wv<<<14, 256, 0, stream>>>(W1, W2, W3, V1, V2, V3, WV);
    k_binsort<<<NBLK, 256, 0, stream>>>(pos, eag, esrc, edst, batch,
                                        deg_d, cnt, binbuf);
    k_ztab<<<NN/8, 256, 0, stream>>>(x, WV, Ztab);
    k_yedge<<<BINS * BPB_Y, 256, 0, stream>>>(Ztab, binbuf, cnt, yq);
    k_racc<<<NN/4, 256, 0, stream>>>(yq, deg_d, rtab);
    k_gfinal<<<BINS * BPB_G, 256, 0, stream>>>(rtab, binbuf, cnt, partial);
    k_reduce<<<1, 256, 0, stream>>>(partial, (float*)d_out);
}

// Round 6
// 183.760 us; speedup vs baseline: 1.4249x; 1.0442x over previous
//
#include <hip/hip_runtime.h>

#define NN 20000
#define NE 320000
#define NG 256
#define CAPD 48           // dst-side bucket capacity (yq rows); P(deg>48) ~ 1e-12
#define ZS 148            // Ztab row stride (147 used)
#define YQS 32            // yq row stride in floats = 128 B = exactly one cache line
#define PROWS 32          // partial spread rows
#define BINS 8            // src-range bins (bin = s/2500); Ztab slice 1.48 MB < 4 MB L2/XCD
#define NPB 2500          // nodes per bin
#define NBLK 1250         // binsort blocks (256 edges each)
#define BINW 80           // slots per (block,bin); Binom(256,1/8) mean 32 sd 5.3 -> 9 sigma
#define RECF 12           // record floats: [ea(7) | pk(int: p | bg<<21) | s(int) | px py pz]
#define BPB_Y 320         // yedge blocks per bin  -> grid 2560, ~4 runs/block
#define BPB_G 160         // gfinal blocks per bin -> grid 1280, ~8 runs/block

// binbuf layout: [bin][block][BINW] records, bin-major.
// XCD pinning: consumer blocks take bin = blockIdx.x & 7; HW round-robins blockIdx
// across the 8 XCDs, so each XCD's L2 holds exactly its own Ztab/rtab slice
// (1.5 MB / 0.64 MB) for the whole kernel. Perf heuristic only -- correctness
// never depends on the mapping (any block can process any bin).
// cnt[bin*NBLK + block] = records in that run (dense from slot 0).
// yq row (32 floats): [y(21) | sh(8) | 0,0,0]  -- one aligned 128 B line per edge.
// y col = g*7+v; scale factors folded into WV.

// ---------------- K0: WV[u][147] = folded W*V weights (tiny) ----------------

__global__ __launch_bounds__(256) void k_wv(
    const float* __restrict__ W1, const float* __restrict__ W2,
    const float* __restrict__ W3, const float* __restrict__ V1,
    const float* __restrict__ V2, const float* __restrict__ V3,
    float* __restrict__ WV)
{
    const int idx = blockIdx.x * 256 + threadIdx.x;   // 23*147 = 3381
    if (idx < 23 * 147) {
        const int u = idx / 147, c = idx - u * 147;
        const int vp = c / 21, col = c - vp * 21;
        const int g = col / 7, v = col - g * 7;
        float sum = 0.f;
        if (g == 0) {
            for (int w = 0; w < 64; ++w)
                sum += W1[(u*7 + vp)*64 + w] * V1[w*7 + v];
            sum *= 0.07881104f * 0.04724556f;   // a1 * 1/sqrt(64*7)
        } else if (g == 1) {
            for (int w = 0; w < 24; ++w)
                sum += W2[(u*7 + vp)*24 + w] * V2[w*7 + v];
            sum *= 0.07881104f * 0.04454354f;   // a1 * 1/sqrt(24*7*3)
        } else {
            for (int w = 0; w < 16; ++w)
                sum += W3[(u*7 + vp)*16 + w] * V3[w*7 + v];
            sum *= 0.07881104f * 0.04225771f;   // a1 * 1/sqrt(16*7*5)
        }
        WV[idx] = sum;                           // [u][147], c = v'*21 + col
    }
}

// ---------------- K1: slotted bin scatter -- no barriers around global atomics ----------------

__global__ __launch_bounds__(256) void k_binsort(
    const float* __restrict__ pos,
    const float* __restrict__ eag,
    const int* __restrict__ esrc,
    const int* __restrict__ edst,
    const int* __restrict__ batch,
    int* __restrict__ deg_d,
    int* __restrict__ cnt,
    float* __restrict__ binbuf)
{
    __shared__ int off[BINS];
    const int t = threadIdx.x, bb = blockIdx.x;
    const int e = bb * 256 + t;               // NBLK*256 == NE
    if (t < BINS) off[t] = 0;

    const int s = esrc[e], d = edst[e];
    const int bin = s / NPB;                  // 0..7
    const int sd = atomicAdd(&deg_d[d], 1);   // fired early, used only at the store
    const int bg = batch[d];
    float ea[7];
#pragma unroll
    for (int v = 0; v < 7; ++v) ea[v] = eag[(size_t)e * 7 + v];
    const float px = pos[3*s+0] - pos[3*d+0];
    const float py = pos[3*s+1] - pos[3*d+1];
    const float pz = pos[3*s+2] - pos[3*d+2];

    __syncthreads();                          // off init visible (LDS only)
    const bool ok = (sd < CAPD);              // overflow edge dropped (P ~ 0)
    int slot = BINW;
    if (ok) slot = atomicAdd(&off[bin], 1);   // LDS atomic, no global sequencing
    if (ok && slot < BINW) {
        const int pk = (d * CAPD + sd) | (bg << 21);   // p < 960000 < 2^20
        float4* r = (float4*)(binbuf + (((size_t)bin * NBLK + bb) * BINW + slot) * RECF);
        r[0] = make_float4(ea[0], ea[1], ea[2], ea[3]);
        r[1] = make_float4(ea[4], ea[5], ea[6], __int_as_float(pk));
        r[2] = make_float4(__int_as_float(s), px, py, pz);
    }
    __syncthreads();
    if (t < BINS) cnt[t * NBLK + bb] = min(off[t], BINW);
}

// ---------------- K2: Ztab[n][c] = sum_u x[n][u] * WV[u][c]  (8 nodes/block) ----------------

__global__ __launch_bounds__(256) void k_ztab(const float* __restrict__ x,
                                              const float* __restrict__ WV,
                                              float* __restrict__ Ztab)
{
    __shared__ float xa[8][23];
    const int b = blockIdx.x, t = threadIdx.x;   // grid 2500 exact
    const int base = b * 8;
    if (t < 184) {
        const int nl = t / 23, u = t - nl * 23;
        xa[nl][u] = x[(size_t)(base + nl) * 23 + u];
    }
    __syncthreads();
    if (t < 147) {
        float acc[8];
#pragma unroll
        for (int n = 0; n < 8; ++n) acc[n] = 0.f;
        for (int u = 0; u < 23; ++u) {
            const float wv = WV[u * 147 + t];     // coalesced
#pragma unroll
            for (int n = 0; n < 8; ++n) acc[n] += xa[n][u] * wv;
        }
#pragma unroll
        for (int n = 0; n < 8; ++n)
            Ztab[(size_t)(base + n) * ZS + t] = acc[n];
    }
}

// ---------------- K3: XCD-pinned persistent blocks; 32 lanes/record ----------
// bin = blockIdx.x & 7 keeps each bin's blocks on one XCD -> Ztab slice L2-resident.

__global__ __launch_bounds__(256) void k_yedge(const float* __restrict__ Ztab,
                                               const float* __restrict__ binbuf,
                                               const int* __restrict__ cnt,
                                               float* __restrict__ yq)
{
    const int t = threadIdx.x;
    const int bin = blockIdx.x & 7;             // grid = 8 * BPB_Y = 2560
    const int bb0 = blockIdx.x >> 3;
    const int grp = t >> 5, col = t & 31;       // 8 groups of 32 lanes

    for (int bb = bb0; bb < NBLK; bb += BPB_Y) {
        const int cn = cnt[bin * NBLK + bb];    // uniform per block -> scalar load
        const float* run = binbuf + ((size_t)(bin * NBLK + bb) * BINW) * RECF;
        for (int idx = grp; idx < cn; idx += 8) {
            const float* rec = run + (size_t)idx * RECF;
            const int p = ((const int*)rec)[7] & 0x1FFFFF;
            float val;
            if (col < 21) {
                const int s = ((const int*)rec)[8];
                const float* z = Ztab + (size_t)s * ZS;
                float y = 0.f;
#pragma unroll
                for (int v = 0; v < 7; ++v)
                    y += rec[v] * z[21 * v + col];
                val = y;
            } else if (col < 29) {
                const float px = rec[9], py = rec[10], pz = rec[11];
                const float r2 = px*px + py*py + pz*pz;
                const float h0 = 1.7320508f*px, h1 = 1.7320508f*py, h2 = 1.7320508f*pz;
                const float h3 = 3.8729833f*px*py, h4 = 3.8729833f*py*pz;
                const float h5 = 1.1180340f*(3.f*pz*pz - r2);
                const float h6 = 3.8729833f*px*pz;
                const float h7 = 1.9364917f*(px*px - py*py);
                const int c = col - 21;
                val = (c == 0) ? h0 : (c == 1) ? h1 : (c == 2) ? h2 : (c == 3) ? h3
                    : (c == 4) ? h4 : (c == 5) ? h5 : (c == 6) ? h6 : h7;
            } else {
                val = 0.f;
            }
            yq[(size_t)p * YQS + col] = val;    // one aligned 128 B line per record
        }
    }
}

// ---------------- K4: wave per dst node; single-stream reduction of its bucket ----------------
// rtab row (64 fp32): [r0[v](7) | r1[m,v] m-major (21) | r2[m,v] m-major (35) | pad]

__global__ __launch_bounds__(256) void k_racc(const float* __restrict__ yq,
                                              const int* __restrict__ deg_d,
                                              float* __restrict__ rtab)
{
    const int t = threadIdx.x, lane = t & 63;
    const int node = __builtin_amdgcn_readfirstlane(blockIdx.x * 4 + (t >> 6));
    const int dg = min(deg_d[node], CAPD);

    int col, sidx; bool unit;
    if (lane < 7)       { col = lane;              sidx = 0;          unit = true;  }
    else if (lane < 28) { const int i = lane - 7;  col = 7  + i % 7;  sidx = i / 7;     unit = false; }
    else if (lane < 63) { const int i = lane - 28; col = 14 + i % 7;  sidx = 3 + i / 7; unit = false; }
    else                { col = 0;                 sidx = 0;          unit = true;  }

    const float* yb = yq + (size_t)node * (CAPD * YQS);

    float acc = 0.f;
    int r = 0;
    for (; r + 4 <= dg; r += 4) {
        float yv[4], sv[4];
#pragma unroll
        for (int k = 0; k < 4; ++k) yv[k] = yb[(r + k) * YQS + col];
#pragma unroll
        for (int k = 0; k < 4; ++k) sv[k] = yb[(r + k) * YQS + 21 + sidx];
#pragma unroll
        for (int k = 0; k < 4; ++k) acc += (unit ? 1.f : sv[k]) * yv[k];
    }
    for (; r < dg; ++r) {
        const float yv = yb[r * YQS + col];
        const float sv = yb[r * YQS + 21 + sidx];
        acc += (unit ? 1.f : sv) * yv;
    }

    rtab[(size_t)node * 64 + lane] = (lane < 63) ? acc : 0.f;
}

// ---------------- K5: XCD-pinned persistent blocks; 8 lanes/record ----------

__global__ __launch_bounds__(256) void k_gfinal(const float* __restrict__ rtab,
                                                const float* __restrict__ binbuf,
                                                const int* __restrict__ cnt,
                                                float* __restrict__ partial)
{
    __shared__ float bins_s[NG];
    const int t = threadIdx.x;
    const int bin = blockIdx.x & 7;             // grid = 8 * BPB_G = 1280
    const int bb0 = blockIdx.x >> 3;
    const int grp = t >> 3, v = t & 7;          // 32 groups; v = 0..6 active

    bins_s[t] = 0.f;
    __syncthreads();

    for (int bb = bb0; bb < NBLK; bb += BPB_G) {
        const int cn = cnt[bin * NBLK + bb];    // uniform per block -> scalar load
        const float* run = binbuf + ((size_t)(bin * NBLK + bb) * BINW) * RECF;
        for (int idx = grp; idx < cn; idx += 32) {
            const float* rec = run + (size_t)idx * RECF;
            const int pk = ((const int*)rec)[7];
            const int bg = ((unsigned)pk) >> 21;
            const int s  = ((const int*)rec)[8];
            const float px = rec[9], py = rec[10], pz = rec[11];
            const float r2 = px*px + py*py + pz*pz;
            const float h0 = 1.7320508f*px, h1 = 1.7320508f*py, h2 = 1.7320508f*pz;
            const float h3 = 3.8729833f*px*py, h4 = 3.8729833f*py*pz;
            const float h5 = 1.1180340f*(3.f*pz*pz - r2);
            const float h6 = 3.8729833f*px*pz;
            const float h7 = 1.9364917f*(px*px - py*py);

            const float* r = rtab + (size_t)s * 64;
            const float eav = (v < 7) ? rec[v] : 0.f;

            float tsum = r[v];                  // shfac[0] = 1
            tsum += h0 * r[ 7 + v];
            tsum += h1 * r[14 + v];
            tsum += h2 * r[21 + v];
            tsum += h3 * r[28 + v];
            tsum += h4 * r[35 + v];
            tsum += h5 * r[42 + v];
            tsum += h6 * r[49 + v];
            tsum += h7 * r[56 + v];

            float g = eav * tsum;
            g += __shfl_xor(g, 1);              // reduce 8-lane group
            g += __shfl_xor(g, 2);
            g += __shfl_xor(g, 4);
            if (v == 0) atomicAdd(&bins_s[bg], g);  // LDS atomic, 1 per record
        }
    }

    __syncthreads();
    unsafeAtomicAdd(&partial[(blockIdx.x & (PROWS - 1)) * NG + t], bins_s[t]);
}

// ---------------- K6: reduce PROWS partial rows -> out ----------------

__global__ __launch_bounds__(256) void k_reduce(const float* __restrict__ partial,
                                                float* __restrict__ out)
{
    const int t = threadIdx.x;
    float s = 0.f;
#pragma unroll
    for (int i = 0; i < PROWS; ++i) s += partial[i * NG + t];
    out[t] = s;
}

extern "C" void kernel_launch(void* const* d_in, const int* in_sizes, int n_in,
                              void* d_out, int out_size, void* d_ws, size_t ws_size,
                              hipStream_t stream)
{
    const float* pos  = (const float*)d_in[0];
    const float* x    = (const float*)d_in[1];
    const float* eag  = (const float*)d_in[2];
    const int*   eidx = (const int*)d_in[3];
    const int*   batch= (const int*)d_in[4];
    const float* W1   = (const float*)d_in[5];
    const float* W2   = (const float*)d_in[6];
    const float* W3   = (const float*)d_in[7];
    const float* V1   = (const float*)d_in[8];
    const float* V2   = (const float*)d_in[9];
    const float* V3   = (const float*)d_in[10];
    const int* esrc = eidx;
    const int* edst = eidx + NE;

    char* ws = (char*)d_ws;
    size_t off = 0;
    auto alloc = [&](size_t bytes) -> void* {
        void* p = ws + off;
        off = (off + bytes + 255) & ~(size_t)255;
        return p;
    };
    float* yq     = (float*)alloc((size_t)NN * CAPD * YQS * sizeof(float)); // 122.9 MB
    float* binbuf = (float*)alloc((size_t)BINS * NBLK * BINW * RECF * sizeof(float)); // 38.4 MB
    float* Ztab   = (float*)alloc((size_t)NN * ZS * sizeof(float));         // 11.8 MB
    float* rtab   = (float*)alloc((size_t)NN * 64 * sizeof(float));         // 5.1 MB
    float* WV     = (float*)alloc((size_t)23 * 147 * sizeof(float));        // 13.5 KB
    int*   cnt    = (int*)alloc((size_t)BINS * NBLK * sizeof(int));         // 40 KB (rewritten)
    int*   deg_d  = (int*)alloc((size_t)NN * sizeof(int));     // ---- zeroed region
    float* partial= (float*)alloc((size_t)PROWS * NG * sizeof(float));
    char*  zend   = (char*)ws + off;

    hipMemsetAsync(deg_d, 0, (size_t)(zend - (char*)deg_d), stream);

    k_wv<<<14, 256, 0, stream>>>(W1, W2, W3, V1, V2, V3, WV);
    k_binsort<<<NBLK, 256, 0, stream>>>(pos, eag, esrc, edst, batch,
                                        deg_d, cnt, binbuf);
    k_ztab<<<NN/8, 256, 0, stream>>>(x, WV, Ztab);
    k_yedge<<<BINS * BPB_Y, 256, 0, stream>>>(Ztab, binbuf, cnt, yq);
    k_racc<<<NN/4, 256, 0, stream>>>(yq, deg_d, rtab);
    k_gfinal<<<BINS * BPB_G, 256, 0, stream>>>(rtab, binbuf, cnt, partial);
    k_reduce<<<1, 256, 0, stream>>>(partial, (float*)d_out);
}

// Round 8
// 173.577 us; speedup vs baseline: 1.5085x; 1.0587x over previous
//
#include <hip/hip_runtime.h>

#define NN 20000
#define NE 320000
#define NG 256
#define CAPD 48           // dst-side bucket capacity (yq rows); P(deg>48) ~ 1e-12
#define ZS 148            // Ztab row stride (147 used)
#define YQS 32            // yq row stride in floats = 128 B = exactly one cache line
#define PROWS 32          // partial spread rows
#define BINS 8            // src-range bins (bin = s/2500); Ztab slice 1.48 MB < 4 MB L2/XCD
#define NPB 2500          // nodes per bin
#define NBLK 1250         // binsort blocks (256 edges each)
#define BINW 80           // slots per (block,bin); Binom(256,1/8) mean 32 sd 5.3 -> 9 sigma
#define RECF 12           // record floats: [ea(7) | pk(int: p | bg<<21) | s(int) | px py pz]
#define BPB_Y 320         // yedge blocks per bin  -> grid 2560, ~4 runs/block
#define BPB_G 160         // gfinal blocks per bin -> grid 1280, ~8 runs/block

// binbuf layout: [bin][block][BINW] records, bin-major.
// XCD pinning: consumer blocks take bin = blockIdx.x & 7; HW round-robins blockIdx
// across the 8 XCDs, so each XCD's L2 holds exactly its own Ztab/rtab slice.
// Consumers use depth-1 register prefetch of the next record; k_gfinal's
// iteration is flattened over (run, slot) so ALL slots are covered (round-7 bug:
// the prefetch rewrite dropped slots >= 32 -> 6% of edges lost).
// cnt[bin*NBLK + block] = records in that run (dense from slot 0).
// yq row (32 floats): [y(21) | sh(8) | 0,0,0]  -- one aligned 128 B line per edge.
// y col = g*7+v; scale factors folded into WV.

// ---------------- K1: blocks < NBLK: slotted bin scatter; rest: WV build ----------------

__global__ __launch_bounds__(256) void k_binsort(
    const float* __restrict__ pos,
    const float* __restrict__ eag,
    const int* __restrict__ esrc,
    const int* __restrict__ edst,
    const int* __restrict__ batch,
    const float* __restrict__ W1,
    const float* __restrict__ W2,
    const float* __restrict__ W3,
    const float* __restrict__ V1,
    const float* __restrict__ V2,
    const float* __restrict__ V3,
    int* __restrict__ deg_d,
    int* __restrict__ cnt,
    float* __restrict__ binbuf,
    float* __restrict__ WV)
{
    const int t = threadIdx.x, bb = blockIdx.x;
    if (bb >= NBLK) {
        const int idx = (bb - NBLK) * 256 + t;   // WV: 23*147 = 3381
        if (idx < 23 * 147) {
            const int u = idx / 147, c = idx - u * 147;
            const int vp = c / 21, col = c - vp * 21;
            const int g = col / 7, v = col - g * 7;
            float sum = 0.f;
            if (g == 0) {
                for (int w = 0; w < 64; ++w)
                    sum += W1[(u*7 + vp)*64 + w] * V1[w*7 + v];
                sum *= 0.07881104f * 0.04724556f;   // a1 * 1/sqrt(64*7)
            } else if (g == 1) {
                for (int w = 0; w < 24; ++w)
                    sum += W2[(u*7 + vp)*24 + w] * V2[w*7 + v];
                sum *= 0.07881104f * 0.04454354f;   // a1 * 1/sqrt(24*7*3)
            } else {
                for (int w = 0; w < 16; ++w)
                    sum += W3[(u*7 + vp)*16 + w] * V3[w*7 + v];
                sum *= 0.07881104f * 0.04225771f;   // a1 * 1/sqrt(16*7*5)
            }
            WV[idx] = sum;                           // [u][147], c = v'*21 + col
        }
        return;
    }

    __shared__ int off[BINS];
    const int e = bb * 256 + t;               // NBLK*256 == NE
    if (t < BINS) off[t] = 0;

    const int s = esrc[e], d = edst[e];
    const int bin = s / NPB;                  // 0..7
    const int sd = atomicAdd(&deg_d[d], 1);   // fired early, used only at the store
    const int bg = batch[d];
    float ea[7];
#pragma unroll
    for (int v = 0; v < 7; ++v) ea[v] = eag[(size_t)e * 7 + v];
    const float px = pos[3*s+0] - pos[3*d+0];
    const float py = pos[3*s+1] - pos[3*d+1];
    const float pz = pos[3*s+2] - pos[3*d+2];

    __syncthreads();                          // off init visible (LDS only)
    const bool ok = (sd < CAPD);              // overflow edge dropped (P ~ 0)
    int slot = BINW;
    if (ok) slot = atomicAdd(&off[bin], 1);   // LDS atomic, no global sequencing
    if (ok && slot < BINW) {
        const int pk = (d * CAPD + sd) | (bg << 21);   // p < 960000 < 2^20
        float4* r = (float4*)(binbuf + (((size_t)bin * NBLK + bb) * BINW + slot) * RECF);
        r[0] = make_float4(ea[0], ea[1], ea[2], ea[3]);
        r[1] = make_float4(ea[4], ea[5], ea[6], __int_as_float(pk));
        r[2] = make_float4(__int_as_float(s), px, py, pz);
    }
    __syncthreads();
    if (t < BINS) cnt[t * NBLK + bb] = min(off[t], BINW);
}

// ---------------- K2: Ztab[n][c] = sum_u x[n][u] * WV[u][c]  (8 nodes/block) ----------------

__global__ __launch_bounds__(256) void k_ztab(const float* __restrict__ x,
                                              const float* __restrict__ WV,
                                              float* __restrict__ Ztab)
{
    __shared__ float xa[8][23];
    const int b = blockIdx.x, t = threadIdx.x;   // grid 2500 exact
    const int base = b * 8;
    if (t < 184) {
        const int nl = t / 23, u = t - nl * 23;
        xa[nl][u] = x[(size_t)(base + nl) * 23 + u];
    }
    __syncthreads();
    if (t < 147) {
        float acc[8];
#pragma unroll
        for (int n = 0; n < 8; ++n) acc[n] = 0.f;
        for (int u = 0; u < 23; ++u) {
            const float wv = WV[u * 147 + t];     // coalesced
#pragma unroll
            for (int n = 0; n < 8; ++n) acc[n] += xa[n][u] * wv;
        }
#pragma unroll
        for (int n = 0; n < 8; ++n)
            Ztab[(size_t)(base + n) * ZS + t] = acc[n];
    }
}

// ---------------- K3: XCD-pinned persistent blocks; 32 lanes/record; reg prefetch ----------

__global__ __launch_bounds__(256) void k_yedge(const float* __restrict__ Ztab,
                                               const float* __restrict__ binbuf,
                                               const int* __restrict__ cnt,
                                               float* __restrict__ yq)
{
    const int t = threadIdx.x;
    const int bin = blockIdx.x & 7;             // grid = 8 * BPB_Y = 2560
    const int bb0 = blockIdx.x >> 3;
    const int grp = t >> 5, col = t & 31;       // 8 groups of 32 lanes

    for (int bb = bb0; bb < NBLK; bb += BPB_Y) {
        const int cn = cnt[bin * NBLK + bb];    // uniform per block -> scalar load
        if (grp >= cn) continue;
        const float4* run = (const float4*)(binbuf + ((size_t)(bin * NBLK + bb) * BINW) * RECF);
        int idx = grp;
        float4 r0 = run[idx*3+0], r1 = run[idx*3+1], r2 = run[idx*3+2];
        while (true) {
            const int nidx = idx + 8;
            const bool has = nidx < cn;
            float4 n0, n1, n2;
            if (has) {                          // prefetch next record (HBM latency
                n0 = run[nidx*3+0];             //  hides under z-dot + store below)
                n1 = run[nidx*3+1];
                n2 = run[nidx*3+2];
            }
            const int p = __float_as_int(r1.w) & 0x1FFFFF;
            float val;
            if (col < 21) {
                const int s = __float_as_int(r2.x);
                const float* z = Ztab + (size_t)s * ZS;
                val = r0.x*z[col]      + r0.y*z[21+col]  + r0.z*z[42+col]
                    + r0.w*z[63+col]   + r1.x*z[84+col]  + r1.y*z[105+col]
                    + r1.z*z[126+col];
            } else if (col < 29) {
                const float px = r2.y, py = r2.z, pz = r2.w;
                const float r2s = px*px + py*py + pz*pz;
                const float h0 = 1.7320508f*px, h1 = 1.7320508f*py, h2 = 1.7320508f*pz;
                const float h3 = 3.8729833f*px*py, h4 = 3.8729833f*py*pz;
                const float h5 = 1.1180340f*(3.f*pz*pz - r2s);
                const float h6 = 3.8729833f*px*pz;
                const float h7 = 1.9364917f*(px*px - py*py);
                const int c = col - 21;
                val = (c == 0) ? h0 : (c == 1) ? h1 : (c == 2) ? h2 : (c == 3) ? h3
                    : (c == 4) ? h4 : (c == 5) ? h5 : (c == 6) ? h6 : h7;
            } else {
                val = 0.f;
            }
            yq[(size_t)p * YQS + col] = val;    // one aligned 128 B line per record
            if (!has) break;
            idx = nidx; r0 = n0; r1 = n1; r2 = n2;
        }
    }
}

// ---------------- K4: wave per dst node; single-stream reduction of its bucket ----------------
// rtab row (64 fp32): [r0[v](7) | r1[m,v] m-major (21) | r2[m,v] m-major (35) | pad]

__global__ __launch_bounds__(256) void k_racc(const float* __restrict__ yq,
                                              const int* __restrict__ deg_d,
                                              float* __restrict__ rtab)
{
    const int t = threadIdx.x, lane = t & 63;
    const int node = __builtin_amdgcn_readfirstlane(blockIdx.x * 4 + (t >> 6));
    const int dg = min(deg_d[node], CAPD);

    int col, sidx; bool unit;
    if (lane < 7)       { col = lane;              sidx = 0;          unit = true;  }
    else if (lane < 28) { const int i = lane - 7;  col = 7  + i % 7;  sidx = i / 7;     unit = false; }
    else if (lane < 63) { const int i = lane - 28; col = 14 + i % 7;  sidx = 3 + i / 7; unit = false; }
    else                { col = 0;                 sidx = 0;          unit = true;  }

    const float* yb = yq + (size_t)node * (CAPD * YQS);

    float acc = 0.f;
    int r = 0;
    for (; r + 4 <= dg; r += 4) {
        float yv[4], sv[4];
#pragma unroll
        for (int k = 0; k < 4; ++k) yv[k] = yb[(r + k) * YQS + col];
#pragma unroll
        for (int k = 0; k < 4; ++k) sv[k] = yb[(r + k) * YQS + 21 + sidx];
#pragma unroll
        for (int k = 0; k < 4; ++k) acc += (unit ? 1.f : sv[k]) * yv[k];
    }
    for (; r < dg; ++r) {
        const float yv = yb[r * YQS + col];
        const float sv = yb[r * YQS + 21 + sidx];
        acc += (unit ? 1.f : sv) * yv;
    }

    rtab[(size_t)node * 64 + lane] = (lane < 63) ? acc : 0.f;
}

// ---------------- K5: XCD-pinned persistent blocks; 8 lanes/record ----------
// Flattened (run, slot) walk with depth-1 prefetch: successor of (bb, idx) is
// (bb, idx+32) if idx+32 < cn else (bb+BPB_G, grp) -- known before compute, so
// the next record is always prefetchable and ALL slots are covered.

__global__ __launch_bounds__(256) void k_gfinal(const float* __restrict__ rtab,
                                                const float* __restrict__ binbuf,
                                                const int* __restrict__ cnt,
                                                float* __restrict__ partial)
{
    __shared__ float bins_s[NG];
    const int t = threadIdx.x;
    const int bin = blockIdx.x & 7;             // grid = 8 * BPB_G = 1280
    const int bb0 = blockIdx.x >> 3;
    const int grp = t >> 3, v = t & 7;          // 32 groups of 8; v = 0..6 active

    bins_s[t] = 0.f;
    __syncthreads();

    int bb = bb0, idx = grp;
    int cn = cnt[bin * NBLK + bb];
    const float4* run = (const float4*)(binbuf + ((size_t)(bin * NBLK + bb) * BINW) * RECF);
    float4 r0 = run[idx*3+0], r1 = run[idx*3+1], r2 = run[idx*3+2];  // always in-bounds (idx < BINW)

    while (true) {
        // successor state (computable now: cn already loaded)
        int nbb = bb, nidx = idx + 32, ncn = cn;
        if (nidx >= cn) { nbb = bb + BPB_G; nidx = grp; }
        const bool has = nbb < NBLK;
        float4 n0, n1, n2;
        if (has) {
            const float4* nrun = (const float4*)(binbuf + ((size_t)(bin * NBLK + nbb) * BINW) * RECF);
            n0 = nrun[nidx*3+0]; n1 = nrun[nidx*3+1]; n2 = nrun[nidx*3+2];
            if (nbb != bb) ncn = cnt[bin * NBLK + nbb];
        }
        if (idx < cn) {
            const int pk = __float_as_int(r1.w);
            const int bg = ((unsigned)pk) >> 21;
            const int s  = __float_as_int(r2.x);
            const float px = r2.y, py = r2.z, pz = r2.w;
            const float r2s = px*px + py*py + pz*pz;
            const float h0 = 1.7320508f*px, h1 = 1.7320508f*py, h2 = 1.7320508f*pz;
            const float h3 = 3.8729833f*px*py, h4 = 3.8729833f*py*pz;
            const float h5 = 1.1180340f*(3.f*pz*pz - r2s);
            const float h6 = 3.8729833f*px*pz;
            const float h7 = 1.9364917f*(px*px - py*py);

            const float* r = rtab + (size_t)s * 64;
            float eav = (v == 0) ? r0.x : (v == 1) ? r0.y : (v == 2) ? r0.z
                      : (v == 3) ? r0.w : (v == 4) ? r1.x : (v == 5) ? r1.y : r1.z;
            if (v >= 7) eav = 0.f;

            float tsum = r[v];                  // shfac[0] = 1
            tsum += h0 * r[ 7 + v];
            tsum += h1 * r[14 + v];
            tsum += h2 * r[21 + v];
            tsum += h3 * r[28 + v];
            tsum += h4 * r[35 + v];
            tsum += h5 * r[42 + v];
            tsum += h6 * r[49 + v];
            tsum += h7 * r[56 + v];

            float g = eav * tsum;
            g += __shfl_xor(g, 1);              // reduce 8-lane group
            g += __shfl_xor(g, 2);
            g += __shfl_xor(g, 4);
            if (v == 0) atomicAdd(&bins_s[bg], g);  // LDS atomic, 1 per record
        }
        if (!has) break;
        bb = nbb; idx = nidx; cn = ncn;
        r0 = n0; r1 = n1; r2 = n2;
    }

    __syncthreads();
    unsafeAtomicAdd(&partial[(blockIdx.x & (PROWS - 1)) * NG + t], bins_s[t]);
}

// ---------------- K6: reduce PROWS partial rows -> out ----------------

__global__ __launch_bounds__(256) void k_reduce(const float* __restrict__ partial,
                                                float* __restrict__ out)
{
    const int t = threadIdx.x;
    float s = 0.f;
#pragma unroll
    for (int i = 0; i < PROWS; ++i) s += partial[i * NG + t];
    out[t] = s;
}

extern "C" void kernel_launch(void* const* d_in, const int* in_sizes, int n_in,
                              void* d_out, int out_size, void* d_ws, size_t ws_size,
                              hipStream_t stream)
{
    const float* pos  = (const float*)d_in[0];
    const float* x    = (const float*)d_in[1];
    const float* eag  = (const float*)d_in[2];
    const int*   eidx = (const int*)d_in[3];
    const int*   batch= (const int*)d_in[4];
    const float* W1   = (const float*)d_in[5];
    const float* W2   = (const float*)d_in[6];
    const float* W3   = (const float*)d_in[7];
    const float* V1   = (const float*)d_in[8];
    const float* V2   = (const float*)d_in[9];
    const float* V3   = (const float*)d_in[10];
    const int* esrc = eidx;
    const int* edst = eidx + NE;

    char* ws = (char*)d_ws;
    size_t off = 0;
    auto alloc = [&](size_t bytes) -> void* {
        void* p = ws + off;
        off = (off + bytes + 255) & ~(size_t)255;
        return p;
    };
    float* yq     = (float*)alloc((size_t)NN * CAPD * YQS * sizeof(float)); // 122.9 MB
    float* binbuf = (float*)alloc((size_t)BINS * NBLK * BINW * RECF * sizeof(float)); // 38.4 MB
    float* Ztab   = (float*)alloc((size_t)NN * ZS * sizeof(float));         // 11.8 MB
    float* rtab   = (float*)alloc((size_t)NN * 64 * sizeof(float));         // 5.1 MB
    float* WV     = (float*)alloc((size_t)23 * 147 * sizeof(float));        // 13.5 KB
    int*   cnt    = (int*)alloc((size_t)BINS * NBLK * sizeof(int));         // 40 KB (rewritten)
    int*   deg_d  = (int*)alloc((size_t)NN * sizeof(int));     // ---- zeroed region
    float* partial= (float*)alloc((size_t)PROWS * NG * sizeof(float));
    char*  zend   = (char*)ws + off;

    hipMemsetAsync(deg_d, 0, (size_t)(zend - (char*)deg_d), stream);

    k_binsort<<<NBLK + 14, 256, 0, stream>>>(pos, eag, esrc, edst, batch,
                                             W1, W2, W3, V1, V2, V3,
                                             deg_d, cnt, binbuf, WV);
    k_ztab<<<NN/8, 256, 0, stream>>>(x, WV, Ztab);
    k_yedge<<<BINS * BPB_Y, 256, 0, stream>>>(Ztab, binbuf, cnt, yq);
    k_racc<<<NN/4, 256, 0, stream>>>(yq, deg_d, rtab);
    k_gfinal<<<BINS * BPB_G, 256, 0, stream>>>(rtab, binbuf, cnt, partial);
    k_reduce<<<1, 256, 0, stream>>>(partial, (float*)d_out);
}